// Round 1
// baseline (606.728 us; speedup 1.0000x reference)
//
#include <hip/hip_runtime.h>
#include <cstdint>

typedef int i32x4 __attribute__((ext_vector_type(4)));
typedef int i32x16 __attribute__((ext_vector_type(16)));

#define M_DIM 8192
#define N_DIM 11008
#define K_DIM 4096

// ws layout (bytes)
#define WS_AMAX_OFF   0                      // 1024 floats
#define WS_WSUM_OFF   4096                   // 1024 doubles
#define WS_SCALES_OFF 12288                  // 4 floats
#define WS_QX_OFF     16384                  // 8192*4096 int8
#define WS_TW_OFF     (16384 + 33554432)     // 11008*4096 int8

__device__ __forceinline__ void gload_lds16(const void* g, void* l) {
  __builtin_amdgcn_global_load_lds(
      (const __attribute__((address_space(1))) unsigned int*)g,
      (__attribute__((address_space(3))) unsigned int*)l, 16, 0, 0);
}

// ---------------- reductions ----------------

__global__ void reduce_amax(const float* __restrict__ x, float* __restrict__ partial, int n4) {
  const float4* xv = (const float4*)x;
  float m = 0.f;
  for (long i = (long)blockIdx.x * blockDim.x + threadIdx.x; i < n4;
       i += (long)gridDim.x * blockDim.x) {
    float4 v = xv[i];
    m = fmaxf(m, fmaxf(fmaxf(fabsf(v.x), fabsf(v.y)), fmaxf(fabsf(v.z), fabsf(v.w))));
  }
  __shared__ float sm[256];
  sm[threadIdx.x] = m;
  __syncthreads();
  for (int s = 128; s > 0; s >>= 1) {
    if (threadIdx.x < s) sm[threadIdx.x] = fmaxf(sm[threadIdx.x], sm[threadIdx.x + s]);
    __syncthreads();
  }
  if (threadIdx.x == 0) partial[blockIdx.x] = sm[0];
}

__global__ void reduce_wsum(const float* __restrict__ w, double* __restrict__ partial, int n4) {
  const float4* wv = (const float4*)w;
  double acc = 0.0;
  for (long i = (long)blockIdx.x * blockDim.x + threadIdx.x; i < n4;
       i += (long)gridDim.x * blockDim.x) {
    float4 v = wv[i];
    acc += (double)fabsf(v.x) + (double)fabsf(v.y) + (double)fabsf(v.z) + (double)fabsf(v.w);
  }
  __shared__ double sd[256];
  sd[threadIdx.x] = acc;
  __syncthreads();
  for (int s = 128; s > 0; s >>= 1) {
    if (threadIdx.x < s) sd[threadIdx.x] += sd[threadIdx.x + s];
    __syncthreads();
  }
  if (threadIdx.x == 0) partial[blockIdx.x] = sd[0];
}

__global__ void finalize_scales(const float* __restrict__ amax_p,
                                const double* __restrict__ wsum_p,
                                float* __restrict__ scales) {
  __shared__ float sm[1024];
  __shared__ double sd[1024];
  const int t = threadIdx.x;
  sm[t] = amax_p[t];
  sd[t] = wsum_p[t];
  __syncthreads();
  for (int s = 512; s > 0; s >>= 1) {
    if (t < s) {
      sm[t] = fmaxf(sm[t], sm[t + s]);
      sd[t] += sd[t + s];
    }
    __syncthreads();
  }
  if (t == 0) {
    float act_scale = fmaxf(sm[0] / 127.0f, 1e-8f);
    float w_scale = (float)(sd[0] / (double)((long long)N_DIM * K_DIM)) + 1e-8f;
    scales[0] = act_scale;
    scales[1] = w_scale;
    scales[2] = act_scale * w_scale;
  }
}

// ---------------- quantize ----------------

__device__ __forceinline__ int quant_clip(float v, float s, float lim) {
  float r = rintf(v / s);                 // round-half-even, matches jnp.round
  r = fminf(fmaxf(r, -lim), lim);
  return (int)r;
}

__global__ void quant_x(const float* __restrict__ x, const float* __restrict__ scales,
                        int8_t* __restrict__ q) {
  const float s = scales[0];
  const long i = (long)blockIdx.x * blockDim.x + threadIdx.x;  // 16 elems/thread
  const float4* xv = (const float4*)x + (i << 2);
  i32x4 pk;
#pragma unroll
  for (int j = 0; j < 4; ++j) {
    float4 v = xv[j];
    int b0 = quant_clip(v.x, s, 127.f);
    int b1 = quant_clip(v.y, s, 127.f);
    int b2 = quant_clip(v.z, s, 127.f);
    int b3 = quant_clip(v.w, s, 127.f);
    pk[j] = (b0 & 255) | ((b1 & 255) << 8) | ((b2 & 255) << 16) | (b3 << 24);
  }
  *((i32x4*)q + i) = pk;
}

__global__ void tern_w(const float* __restrict__ w, const float* __restrict__ scales,
                       int8_t* __restrict__ q) {
  const float s = scales[1];
  const long i = (long)blockIdx.x * blockDim.x + threadIdx.x;
  const float4* wv = (const float4*)w + (i << 2);
  i32x4 pk;
#pragma unroll
  for (int j = 0; j < 4; ++j) {
    float4 v = wv[j];
    int b0 = quant_clip(v.x, s, 1.f);
    int b1 = quant_clip(v.y, s, 1.f);
    int b2 = quant_clip(v.z, s, 1.f);
    int b3 = quant_clip(v.w, s, 1.f);
    pk[j] = (b0 & 255) | ((b1 & 255) << 8) | ((b2 & 255) << 16) | (b3 << 24);
  }
  *((i32x4*)q + i) = pk;
}

// ---------------- int8 GEMM ----------------
// C[m,n] = sum_k qx[m,k]*tw[n,k]; out = C * out_scale
// 128x128 tile, BK=128. 4 waves, each 64x64 (2x2 frags of 32x32).
// LDS swizzle: slot (row, c) holds global 16B-chunk (c ^ (row&7))  [rule #21]

__global__ __launch_bounds__(256) void gemm_i8(const int8_t* __restrict__ qx,
                                               const int8_t* __restrict__ tw,
                                               const float* __restrict__ scales,
                                               float* __restrict__ out) {
  __shared__ __align__(16) int8_t As[128 * 128];
  __shared__ __align__(16) int8_t Bs[128 * 128];

  const int tid = threadIdx.x;
  const int l = tid & 63;
  const int w = tid >> 6;
  const int wm = (w >> 1) << 6;   // wave row offset in tile
  const int wn = (w & 1) << 6;    // wave col offset

  // supertile: panels of 8 m-tiles x all 86 n-tiles (B tile L2-reuse x8)
  const int TN = N_DIM / 128;     // 86
  int bid = blockIdx.x;
  int p = bid / (8 * TN);
  int r = bid - p * (8 * TN);
  int mi = (p << 3) + (r & 7);
  int ni = r >> 3;
  const long row0 = (long)mi << 7;
  const long col0 = (long)ni << 7;

  // staging: wave w covers rows [w*32, w*32+32); lane l -> row sub (l>>3), lds chunk (l&7)
  // source chunk = (l&7) ^ (row&7) = (l&7) ^ (l>>3)   (rows 8-aligned per instr)
  const int srow = l >> 3;
  const int schunk = (l & 7) ^ srow;
  const int8_t* gA = qx + (row0 + (w << 5) + srow) * (long)K_DIM + (schunk << 4);
  const int8_t* gB = tw + (col0 + (w << 5) + srow) * (long)K_DIM + (schunk << 4);
  int8_t* lA = As + ((w << 5) * 128);
  int8_t* lB = Bs + ((w << 5) * 128);

  i32x16 acc[2][2];
#pragma unroll
  for (int i = 0; i < 2; ++i)
#pragma unroll
    for (int j = 0; j < 2; ++j)
#pragma unroll
      for (int e = 0; e < 16; ++e) acc[i][j][e] = 0;

  const int arow = wm + (l & 31);
  const int brow = wn + (l & 31);
  const int asz = arow & 7;       // same for arow+32 (32 ≡ 0 mod 8)
  const int bsz = brow & 7;
  const int khalf = l >> 5;

  for (int kt = 0; kt < K_DIM / 128; ++kt) {
#pragma unroll
    for (int i = 0; i < 4; ++i) {
      gload_lds16(gA + (long)kt * 128 + (long)(i * 8) * K_DIM, lA + i * 8 * 128);
      gload_lds16(gB + (long)kt * 128 + (long)(i * 8) * K_DIM, lB + i * 8 * 128);
    }
    __syncthreads();
#pragma unroll
    for (int kk = 0; kk < 4; ++kk) {
      const int cc = (kk << 1) + khalf;       // chunk index 0..7
      i32x4 a0 = *(const i32x4*)(As + arow * 128 + ((cc ^ asz) << 4));
      i32x4 a1 = *(const i32x4*)(As + (arow + 32) * 128 + ((cc ^ asz) << 4));
      i32x4 b0 = *(const i32x4*)(Bs + brow * 128 + ((cc ^ bsz) << 4));
      i32x4 b1 = *(const i32x4*)(Bs + (brow + 32) * 128 + ((cc ^ bsz) << 4));
      acc[0][0] = __builtin_amdgcn_mfma_i32_32x32x32_i8(a0, b0, acc[0][0], 0, 0, 0);
      acc[0][1] = __builtin_amdgcn_mfma_i32_32x32x32_i8(a0, b1, acc[0][1], 0, 0, 0);
      acc[1][0] = __builtin_amdgcn_mfma_i32_32x32x32_i8(a1, b0, acc[1][0], 0, 0, 0);
      acc[1][1] = __builtin_amdgcn_mfma_i32_32x32x32_i8(a1, b1, acc[1][1], 0, 0, 0);
    }
    __syncthreads();
  }

  // epilogue: C/D layout (32x32): col = lane&31, row = (reg&3)+8*(reg>>2)+4*(lane>>5)
  const float osc = scales[2];
  const int coll = l & 31;
  const int rbase = (l >> 5) << 2;
#pragma unroll
  for (int fi = 0; fi < 2; ++fi)
#pragma unroll
    for (int fj = 0; fj < 2; ++fj)
#pragma unroll
      for (int reg = 0; reg < 16; ++reg) {
        int rr = wm + (fi << 5) + rbase + (reg & 3) + ((reg >> 2) << 3);
        int cc2 = wn + (fj << 5) + coll;
        out[(row0 + rr) * (long)N_DIM + (col0 + cc2)] = (float)acc[fi][fj][reg] * osc;
      }
}

// ---------------- launch ----------------

extern "C" void kernel_launch(void* const* d_in, const int* in_sizes, int n_in,
                              void* d_out, int out_size, void* d_ws, size_t ws_size,
                              hipStream_t stream) {
  const float* x = (const float*)d_in[0];   // [4,2048,4096]
  const float* W = (const float*)d_in[1];   // [11008,4096]
  float* out = (float*)d_out;               // [4,2048,11008]

  char* ws = (char*)d_ws;
  float*  amax_p = (float*)(ws + WS_AMAX_OFF);
  double* wsum_p = (double*)(ws + WS_WSUM_OFF);
  float*  scales = (float*)(ws + WS_SCALES_OFF);
  int8_t* qx = (int8_t*)(ws + WS_QX_OFF);
  int8_t* tw = (int8_t*)(ws + WS_TW_OFF);

  reduce_amax<<<1024, 256, 0, stream>>>(x, amax_p, (M_DIM * (long)K_DIM) / 4);
  reduce_wsum<<<1024, 256, 0, stream>>>(W, wsum_p, (N_DIM * (long)K_DIM) / 4);
  finalize_scales<<<1, 1024, 0, stream>>>(amax_p, wsum_p, scales);
  quant_x<<<(M_DIM * (long)K_DIM) / 16 / 256, 256, 0, stream>>>(x, scales, qx);
  tern_w<<<(N_DIM * (long)K_DIM) / 16 / 256, 256, 0, stream>>>(W, scales, tw);

  const int grid = (M_DIM / 128) * (N_DIM / 128);   // 64*86 = 5504
  gemm_i8<<<grid, 256, 0, stream>>>(qx, tw, scales, out);
}

// Round 2
// 563.231 us; speedup vs baseline: 1.0772x; 1.0772x over previous
//
#include <hip/hip_runtime.h>
#include <cstdint>

typedef int i32x4 __attribute__((ext_vector_type(4)));
typedef int i32x16 __attribute__((ext_vector_type(16)));

#define M_DIM 8192
#define N_DIM 11008
#define K_DIM 4096
#define NT    (K_DIM / 128)   // 32 K-tiles of BK=128

// ws layout (bytes)
#define WS_AMAX_OFF   0                      // 1024 floats
#define WS_WSUM_OFF   4096                   // 1024 doubles
#define WS_SCALES_OFF 12288                  // 4 floats
#define WS_QX_OFF     16384                  // 8192*4096 int8
#define WS_TW_OFF     (16384 + 33554432)     // 11008*4096 int8

__device__ __forceinline__ void gload_lds16(const void* g, void* l) {
  __builtin_amdgcn_global_load_lds(
      (const __attribute__((address_space(1))) unsigned int*)g,
      (__attribute__((address_space(3))) unsigned int*)l, 16, 0, 0);
}

// ---------------- reductions ----------------

__global__ void reduce_amax(const float* __restrict__ x, float* __restrict__ partial, int n4) {
  const float4* xv = (const float4*)x;
  float m = 0.f;
  for (long i = (long)blockIdx.x * blockDim.x + threadIdx.x; i < n4;
       i += (long)gridDim.x * blockDim.x) {
    float4 v = xv[i];
    m = fmaxf(m, fmaxf(fmaxf(fabsf(v.x), fabsf(v.y)), fmaxf(fabsf(v.z), fabsf(v.w))));
  }
  __shared__ float sm[256];
  sm[threadIdx.x] = m;
  __syncthreads();
  for (int s = 128; s > 0; s >>= 1) {
    if (threadIdx.x < s) sm[threadIdx.x] = fmaxf(sm[threadIdx.x], sm[threadIdx.x + s]);
    __syncthreads();
  }
  if (threadIdx.x == 0) partial[blockIdx.x] = sm[0];
}

__global__ void reduce_wsum(const float* __restrict__ w, double* __restrict__ partial, int n4) {
  const float4* wv = (const float4*)w;
  double acc = 0.0;
  for (long i = (long)blockIdx.x * blockDim.x + threadIdx.x; i < n4;
       i += (long)gridDim.x * blockDim.x) {
    float4 v = wv[i];
    acc += (double)fabsf(v.x) + (double)fabsf(v.y) + (double)fabsf(v.z) + (double)fabsf(v.w);
  }
  __shared__ double sd[256];
  sd[threadIdx.x] = acc;
  __syncthreads();
  for (int s = 128; s > 0; s >>= 1) {
    if (threadIdx.x < s) sd[threadIdx.x] += sd[threadIdx.x + s];
    __syncthreads();
  }
  if (threadIdx.x == 0) partial[blockIdx.x] = sd[0];
}

__global__ void finalize_scales(const float* __restrict__ amax_p,
                                const double* __restrict__ wsum_p,
                                float* __restrict__ scales) {
  __shared__ float sm[1024];
  __shared__ double sd[1024];
  const int t = threadIdx.x;
  sm[t] = amax_p[t];
  sd[t] = wsum_p[t];
  __syncthreads();
  for (int s = 512; s > 0; s >>= 1) {
    if (t < s) {
      sm[t] = fmaxf(sm[t], sm[t + s]);
      sd[t] += sd[t + s];
    }
    __syncthreads();
  }
  if (t == 0) {
    float act_scale = fmaxf(sm[0] / 127.0f, 1e-8f);
    float w_scale = (float)(sd[0] / (double)((long long)N_DIM * K_DIM)) + 1e-8f;
    scales[0] = act_scale;
    scales[1] = w_scale;
    scales[2] = act_scale * w_scale;
  }
}

// ---------------- quantize ----------------

__device__ __forceinline__ int quant_clip(float v, float s, float lim) {
  float r = rintf(v / s);                 // round-half-even, matches jnp.round
  r = fminf(fmaxf(r, -lim), lim);
  return (int)r;
}

__global__ void quant_x(const float* __restrict__ x, const float* __restrict__ scales,
                        int8_t* __restrict__ q) {
  const float s = scales[0];
  const long i = (long)blockIdx.x * blockDim.x + threadIdx.x;  // 16 elems/thread
  const float4* xv = (const float4*)x + (i << 2);
  i32x4 pk;
#pragma unroll
  for (int j = 0; j < 4; ++j) {
    float4 v = xv[j];
    int b0 = quant_clip(v.x, s, 127.f);
    int b1 = quant_clip(v.y, s, 127.f);
    int b2 = quant_clip(v.z, s, 127.f);
    int b3 = quant_clip(v.w, s, 127.f);
    pk[j] = (b0 & 255) | ((b1 & 255) << 8) | ((b2 & 255) << 16) | (b3 << 24);
  }
  *((i32x4*)q + i) = pk;
}

__global__ void tern_w(const float* __restrict__ w, const float* __restrict__ scales,
                       int8_t* __restrict__ q) {
  const float s = scales[1];
  const long i = (long)blockIdx.x * blockDim.x + threadIdx.x;
  const float4* wv = (const float4*)w + (i << 2);
  i32x4 pk;
#pragma unroll
  for (int j = 0; j < 4; ++j) {
    float4 v = wv[j];
    int b0 = quant_clip(v.x, s, 1.f);
    int b1 = quant_clip(v.y, s, 1.f);
    int b2 = quant_clip(v.z, s, 1.f);
    int b3 = quant_clip(v.w, s, 1.f);
    pk[j] = (b0 & 255) | ((b1 & 255) << 8) | ((b2 & 255) << 16) | (b3 << 24);
  }
  *((i32x4*)q + i) = pk;
}

// ---------------- int8 GEMM: 256x256 tile, BK=128, counted-vmcnt pipeline ----------------
// C[m,n] = sum_k qx[m,k]*tw[n,k]; out = C * out_scale
// 8 waves (2m x 4n), per-wave 128x64 output = acc[4][2] of 32x32 i32 tiles.
// LDS: A/B 256x128B double-buffered = 128 KiB.
// Swizzle (both-sides, rule #21): LDS slot (row, c) holds global chunk c ^ (row&7).
// Sync per K-tile: issue 8 gload_lds(next) -> vmcnt(8) -> B1 -> reads+MFMA -> lgkmcnt(0) -> B2.
//   B1: all waves' writes of current buffer complete before any wave reads it.
//   B2: all waves' reads of next buffer (prev tile) complete before its overwrite.

__global__ __launch_bounds__(512, 2) void gemm_i8(const int8_t* __restrict__ qx,
                                                  const int8_t* __restrict__ tw,
                                                  const float* __restrict__ scales,
                                                  float* __restrict__ out) {
  __shared__ __align__(16) int8_t lds[4][32768];

  const int tid = threadIdx.x;
  const int l = tid & 63;
  const int w = tid >> 6;

  // ---- block -> tile mapping, 2D XCD chunk (bijective: 1376 = 8*172) ----
  const int bid = blockIdx.x;
  const int xcd = bid & 7;
  const int local = bid >> 3;            // 0..171
  const int ni = local >> 2;             // 0..42
  const int mi = (xcd << 2) + (local & 3);  // 0..31
  const long row0 = (long)mi << 8;
  const long col0 = (long)ni << 8;

  // ---- staging source (pre-swizzled global chunk) ----
  const int srow = tid >> 3;             // 0..63
  const int sch = (tid & 7) ^ (srow & 7);
  const int8_t* pA = qx + (row0 + srow) * (long)K_DIM + (sch << 4);
  const int8_t* pB = tw + (col0 + srow) * (long)K_DIM + (sch << 4);
  const int ldst = w << 10;              // wave-uniform LDS slice

  auto stage = [&](int8_t* dA, int8_t* dB, int kt) {
    const long cb = (long)kt << 7;
#pragma unroll
    for (int i = 0; i < 4; ++i)
      gload_lds16(pA + cb + ((long)i * 64) * K_DIM, dA + i * 8192 + ldst);
#pragma unroll
    for (int i = 0; i < 4; ++i)
      gload_lds16(pB + cb + ((long)i * 64) * K_DIM, dB + i * 8192 + ldst);
  };

  // ---- read-side offsets ----
  const int lane31 = l & 31;
  const int khalf = l >> 5;
  const int swz = l & 7;                 // = row&7 for all fragment rows (32-aligned bases)
  int cOff[4];
#pragma unroll
  for (int ks = 0; ks < 4; ++ks) cOff[ks] = ((((ks << 1) | khalf) ^ swz) << 4);
  const int aRow = ((w >> 2) * 128 + lane31) * 128;   // + mf*4096
  int bRow[2];
  bRow[0] = ((w & 3) * 64 + lane31) * 128;
  bRow[1] = bRow[0] + 32 * 128;

  i32x16 acc[4][2];
#pragma unroll
  for (int mf = 0; mf < 4; ++mf)
#pragma unroll
    for (int nf = 0; nf < 2; ++nf)
#pragma unroll
      for (int e = 0; e < 16; ++e) acc[mf][nf][e] = 0;

  int8_t* cA = lds[0];
  int8_t* cB = lds[2];
  int8_t* nA = lds[1];
  int8_t* nB = lds[3];

  stage(cA, cB, 0);   // prologue: tile 0 in flight (8 loads)

  for (int kt = 0; kt < NT; ++kt) {
    if (kt + 1 < NT) {
      stage(nA, nB, kt + 1);                          // 8 more in flight
      asm volatile("s_waitcnt vmcnt(8)" ::: "memory"); // wait ONLY tile kt's 8
    } else {
      asm volatile("s_waitcnt vmcnt(0)" ::: "memory");
    }
    __builtin_amdgcn_s_barrier();                      // B1
    asm volatile("" ::: "memory");

    // B fragments once per K-tile, held across phases
    i32x4 bf[2][4];
#pragma unroll
    for (int nf = 0; nf < 2; ++nf)
#pragma unroll
      for (int ks = 0; ks < 4; ++ks)
        bf[nf][ks] = *(const i32x4*)(cB + bRow[nf] + cOff[ks]);

#pragma unroll
    for (int mf = 0; mf < 4; ++mf) {
      i32x4 af[4];
#pragma unroll
      for (int ks = 0; ks < 4; ++ks)
        af[ks] = *(const i32x4*)(cA + aRow + mf * 4096 + cOff[ks]);
      __builtin_amdgcn_s_setprio(1);
#pragma unroll
      for (int ks = 0; ks < 4; ++ks) {
        acc[mf][0] = __builtin_amdgcn_mfma_i32_32x32x32_i8(af[ks], bf[0][ks], acc[mf][0], 0, 0, 0);
        acc[mf][1] = __builtin_amdgcn_mfma_i32_32x32x32_i8(af[ks], bf[1][ks], acc[mf][1], 0, 0, 0);
      }
      __builtin_amdgcn_s_setprio(0);
    }

    asm volatile("s_waitcnt lgkmcnt(0)" ::: "memory"); // all LDS reads of this tile done
    __builtin_amdgcn_s_barrier();                      // B2
    asm volatile("" ::: "memory");

    int8_t* t;
    t = cA; cA = nA; nA = t;
    t = cB; cB = nB; nB = t;
  }

  // ---- epilogue: C/D 32x32 layout: col=lane&31, row=(reg&3)+8*(reg>>2)+4*(lane>>5) ----
  const float osc = scales[2];
  const int rbase = khalf << 2;
#pragma unroll
  for (int mf = 0; mf < 4; ++mf)
#pragma unroll
    for (int nf = 0; nf < 2; ++nf)
#pragma unroll
      for (int reg = 0; reg < 16; ++reg) {
        int rr = (w >> 2) * 128 + mf * 32 + rbase + (reg & 3) + ((reg >> 2) << 3);
        int cc = (w & 3) * 64 + nf * 32 + lane31;
        out[(row0 + rr) * (long)N_DIM + (col0 + cc)] = (float)acc[mf][nf][reg] * osc;
      }
}

// ---------------- launch ----------------

extern "C" void kernel_launch(void* const* d_in, const int* in_sizes, int n_in,
                              void* d_out, int out_size, void* d_ws, size_t ws_size,
                              hipStream_t stream) {
  const float* x = (const float*)d_in[0];   // [4,2048,4096]
  const float* W = (const float*)d_in[1];   // [11008,4096]
  float* out = (float*)d_out;               // [4,2048,11008]

  char* ws = (char*)d_ws;
  float*  amax_p = (float*)(ws + WS_AMAX_OFF);
  double* wsum_p = (double*)(ws + WS_WSUM_OFF);
  float*  scales = (float*)(ws + WS_SCALES_OFF);
  int8_t* qx = (int8_t*)(ws + WS_QX_OFF);
  int8_t* tw = (int8_t*)(ws + WS_TW_OFF);

  reduce_amax<<<1024, 256, 0, stream>>>(x, amax_p, (M_DIM * (long)K_DIM) / 4);
  reduce_wsum<<<1024, 256, 0, stream>>>(W, wsum_p, (N_DIM * (long)K_DIM) / 4);
  finalize_scales<<<1, 1024, 0, stream>>>(amax_p, wsum_p, scales);
  quant_x<<<(M_DIM * (long)K_DIM) / 16 / 256, 256, 0, stream>>>(x, scales, qx);
  tern_w<<<(N_DIM * (long)K_DIM) / 16 / 256, 256, 0, stream>>>(W, scales, tw);

  const int grid = (M_DIM / 256) * (N_DIM / 256);   // 32*43 = 1376 = 8*172
  gemm_i8<<<grid, 512, 0, stream>>>(qx, tw, scales, out);
}

// Round 3
// 541.726 us; speedup vs baseline: 1.1200x; 1.0397x over previous
//
#include <hip/hip_runtime.h>
#include <cstdint>

typedef int i32x4 __attribute__((ext_vector_type(4)));
typedef int i32x16 __attribute__((ext_vector_type(16)));

#define M_DIM 8192
#define N_DIM 11008
#define K_DIM 4096
#define NT    (K_DIM / 128)   // 32 K-tiles of BK=128

// ws layout (bytes)
#define WS_AMAX_OFF   0                      // 1024 floats
#define WS_WSUM_OFF   4096                   // 1024 doubles
#define WS_SCALES_OFF 12288                  // 4 floats
#define WS_QX_OFF     16384                  // 8192*4096 int8
#define WS_TW_OFF     (16384 + 33554432)     // 11008*4096 int8

__device__ __forceinline__ void gload_lds16(const void* g, void* l) {
  __builtin_amdgcn_global_load_lds(
      (const __attribute__((address_space(1))) unsigned int*)g,
      (__attribute__((address_space(3))) unsigned int*)l, 16, 0, 0);
}

// ---------------- reductions ----------------

__global__ void reduce_amax(const float* __restrict__ x, float* __restrict__ partial, int n4) {
  const float4* xv = (const float4*)x;
  float m = 0.f;
  for (long i = (long)blockIdx.x * blockDim.x + threadIdx.x; i < n4;
       i += (long)gridDim.x * blockDim.x) {
    float4 v = xv[i];
    m = fmaxf(m, fmaxf(fmaxf(fabsf(v.x), fabsf(v.y)), fmaxf(fabsf(v.z), fabsf(v.w))));
  }
  __shared__ float sm[256];
  sm[threadIdx.x] = m;
  __syncthreads();
  for (int s = 128; s > 0; s >>= 1) {
    if (threadIdx.x < s) sm[threadIdx.x] = fmaxf(sm[threadIdx.x], sm[threadIdx.x + s]);
    __syncthreads();
  }
  if (threadIdx.x == 0) partial[blockIdx.x] = sm[0];
}

__global__ void reduce_wsum(const float* __restrict__ w, double* __restrict__ partial, int n4) {
  const float4* wv = (const float4*)w;
  double acc = 0.0;
  for (long i = (long)blockIdx.x * blockDim.x + threadIdx.x; i < n4;
       i += (long)gridDim.x * blockDim.x) {
    float4 v = wv[i];
    acc += (double)fabsf(v.x) + (double)fabsf(v.y) + (double)fabsf(v.z) + (double)fabsf(v.w);
  }
  __shared__ double sd[256];
  sd[threadIdx.x] = acc;
  __syncthreads();
  for (int s = 128; s > 0; s >>= 1) {
    if (threadIdx.x < s) sd[threadIdx.x] += sd[threadIdx.x + s];
    __syncthreads();
  }
  if (threadIdx.x == 0) partial[blockIdx.x] = sd[0];
}

__global__ void finalize_scales(const float* __restrict__ amax_p,
                                const double* __restrict__ wsum_p,
                                float* __restrict__ scales) {
  __shared__ float sm[1024];
  __shared__ double sd[1024];
  const int t = threadIdx.x;
  sm[t] = amax_p[t];
  sd[t] = wsum_p[t];
  __syncthreads();
  for (int s = 512; s > 0; s >>= 1) {
    if (t < s) {
      sm[t] = fmaxf(sm[t], sm[t + s]);
      sd[t] += sd[t + s];
    }
    __syncthreads();
  }
  if (t == 0) {
    float act_scale = fmaxf(sm[0] / 127.0f, 1e-8f);
    float w_scale = (float)(sd[0] / (double)((long long)N_DIM * K_DIM)) + 1e-8f;
    scales[0] = act_scale;
    scales[1] = w_scale;
    scales[2] = act_scale * w_scale;
  }
}

// ---------------- quantize ----------------

__device__ __forceinline__ int quant_clip(float v, float s, float lim) {
  float r = rintf(v / s);                 // round-half-even, matches jnp.round
  r = fminf(fmaxf(r, -lim), lim);
  return (int)r;
}

__global__ void quant_x(const float* __restrict__ x, const float* __restrict__ scales,
                        int8_t* __restrict__ q) {
  const float s = scales[0];
  const long i = (long)blockIdx.x * blockDim.x + threadIdx.x;  // 16 elems/thread
  const float4* xv = (const float4*)x + (i << 2);
  i32x4 pk;
#pragma unroll
  for (int j = 0; j < 4; ++j) {
    float4 v = xv[j];
    int b0 = quant_clip(v.x, s, 127.f);
    int b1 = quant_clip(v.y, s, 127.f);
    int b2 = quant_clip(v.z, s, 127.f);
    int b3 = quant_clip(v.w, s, 127.f);
    pk[j] = (b0 & 255) | ((b1 & 255) << 8) | ((b2 & 255) << 16) | (b3 << 24);
  }
  *((i32x4*)q + i) = pk;
}

__global__ void tern_w(const float* __restrict__ w, const float* __restrict__ scales,
                       int8_t* __restrict__ q) {
  const float s = scales[1];
  const long i = (long)blockIdx.x * blockDim.x + threadIdx.x;
  const float4* wv = (const float4*)w + (i << 2);
  i32x4 pk;
#pragma unroll
  for (int j = 0; j < 4; ++j) {
    float4 v = wv[j];
    int b0 = quant_clip(v.x, s, 1.f);
    int b1 = quant_clip(v.y, s, 1.f);
    int b2 = quant_clip(v.z, s, 1.f);
    int b3 = quant_clip(v.w, s, 1.f);
    pk[j] = (b0 & 255) | ((b1 & 255) << 8) | ((b2 & 255) << 16) | (b3 << 24);
  }
  *((i32x4*)q + i) = pk;
}

// ---------------- int8 GEMM: 256x256 tile, BK=128, 4-phase interleave ----------------
// 8 waves (2m x 4n), per-wave 128x64 output = acc[4][2] of 32x32 i32 tiles.
// Phase p (= k-slice ks): 6 ds_read_b128 + 2 gload_lds(next tile) + bar + lgkm0
//                         + setprio{8 MFMA} + bar.      (T3+T4+T5, m201 template)
// Boundary: issue tile t+2 part0, s_waitcnt vmcnt(2) (counted, never 0 in steady
// state), barrier. Swizzle (rule #21): LDS slot (row,c) holds global chunk c^(row&7).

__global__ __launch_bounds__(512, 2) void gemm_i8(const int8_t* __restrict__ qx,
                                                  const int8_t* __restrict__ tw,
                                                  const float* __restrict__ scales,
                                                  float* __restrict__ out) {
  __shared__ __align__(16) int8_t lds[4][32768];   // A0,A1,B0,B1

  const int tid = threadIdx.x;
  const int l = tid & 63;
  const int w = tid >> 6;

  // ---- block -> tile mapping, 2D XCD chunk (bijective: 1376 = 8*172) ----
  const int bid = blockIdx.x;
  const int xcd = bid & 7;
  const int local = bid >> 3;               // 0..171
  const int ni = local >> 2;                // 0..42
  const int mi = (xcd << 2) + (local & 3);  // 0..31
  const long row0 = (long)mi << 8;
  const long col0 = (long)ni << 8;

  // ---- staging source (pre-swizzled global chunk) ----
  const int srow = tid >> 3;                // 0..63
  const int sch = (tid & 7) ^ (srow & 7);
  const int8_t* pA = qx + (row0 + srow) * (long)K_DIM + (sch << 4);
  const int8_t* pB = tw + (col0 + srow) * (long)K_DIM + (sch << 4);
  const int ldst = w << 10;                 // wave-uniform LDS slice

  // stage one part (rows part*64 .. part*64+63) of a K-tile: 2 gload_lds per wave
  auto stage_part = [&](int8_t* dA, int8_t* dB, int kt, int part) {
    const long cb = (long)kt << 7;
    gload_lds16(pA + cb + ((long)part * 64) * K_DIM, dA + part * 8192 + ldst);
    gload_lds16(pB + cb + ((long)part * 64) * K_DIM, dB + part * 8192 + ldst);
  };

  // ---- read-side offsets ----
  const int lane31 = l & 31;
  const int khalf = l >> 5;
  const int swz = l & 7;                    // = row&7 (fragment row bases 32-aligned)
  int cOff[4];
#pragma unroll
  for (int ks = 0; ks < 4; ++ks) cOff[ks] = ((((ks << 1) | khalf) ^ swz) << 4);
  const int aRow = ((w >> 2) * 128 + lane31) * 128;   // + mf*4096
  const int bRow0 = ((w & 3) * 64 + lane31) * 128;
  const int bRow1 = bRow0 + 32 * 128;

  i32x16 acc[4][2];
#pragma unroll
  for (int mf = 0; mf < 4; ++mf)
#pragma unroll
    for (int nf = 0; nf < 2; ++nf)
#pragma unroll
      for (int e = 0; e < 16; ++e) acc[mf][nf][e] = 0;

  // ---- prologue: tile0 fully staged, tile1 part0 in flight ----
#pragma unroll
  for (int p = 0; p < 4; ++p) stage_part(lds[0], lds[2], 0, p);
  stage_part(lds[1], lds[3], 1, 0);
  asm volatile("s_waitcnt vmcnt(2)" ::: "memory");
  __builtin_amdgcn_s_barrier();

  for (int t = 0; t < NT; ++t) {
    int8_t* cA = lds[t & 1];
    int8_t* cB = lds[2 + (t & 1)];
    int8_t* nA = lds[(t & 1) ^ 1];
    int8_t* nB = lds[2 + ((t & 1) ^ 1)];
    const bool pf = (t + 1 < NT);

#pragma unroll
    for (int ks = 0; ks < 4; ++ks) {
      // phase reads: one k-slice of all fragments (6 x ds_read_b128)
      i32x4 af[4], b0, b1;
#pragma unroll
      for (int mf = 0; mf < 4; ++mf)
        af[mf] = *(const i32x4*)(cA + aRow + mf * 4096 + cOff[ks]);
      b0 = *(const i32x4*)(cB + bRow0 + cOff[ks]);
      b1 = *(const i32x4*)(cB + bRow1 + cOff[ks]);
      // spread next-tile staging: parts 1..3 in phases 0..2
      if (ks < 3 && pf) stage_part(nA, nB, t + 1, ks + 1);
      asm volatile("" ::: "memory");
      __builtin_amdgcn_s_barrier();
      asm volatile("s_waitcnt lgkmcnt(0)" ::: "memory");
      __builtin_amdgcn_s_setprio(1);
#pragma unroll
      for (int mf = 0; mf < 4; ++mf) {
        acc[mf][0] = __builtin_amdgcn_mfma_i32_32x32x32_i8(af[mf], b0, acc[mf][0], 0, 0, 0);
        acc[mf][1] = __builtin_amdgcn_mfma_i32_32x32x32_i8(af[mf], b1, acc[mf][1], 0, 0, 0);
      }
      __builtin_amdgcn_s_setprio(0);
      asm volatile("" ::: "memory");
      __builtin_amdgcn_s_barrier();
    }

    // tile boundary: issue t+2 part0 (into cur, whose reads just drained),
    // counted vmcnt so t+1's 8 loads are done with t+2's 2 still in flight
    if (pf) {
      if (t + 2 < NT) {
        stage_part(cA, cB, t + 2, 0);
        asm volatile("s_waitcnt vmcnt(2)" ::: "memory");
      } else {
        asm volatile("s_waitcnt vmcnt(0)" ::: "memory");
      }
      __builtin_amdgcn_s_barrier();
    }
  }

  // ---- epilogue: C/D 32x32 layout: col=lane&31, row=(reg&3)+8*(reg>>2)+4*(lane>>5) ----
  const float osc = scales[2];
  const int rbase = khalf << 2;
#pragma unroll
  for (int mf = 0; mf < 4; ++mf)
#pragma unroll
    for (int nf = 0; nf < 2; ++nf)
#pragma unroll
      for (int reg = 0; reg < 16; ++reg) {
        int rr = (w >> 2) * 128 + mf * 32 + rbase + (reg & 3) + ((reg >> 2) << 3);
        int cc = (w & 3) * 64 + nf * 32 + lane31;
        out[(row0 + rr) * (long)N_DIM + (col0 + cc)] = (float)acc[mf][nf][reg] * osc;
      }
}

// ---------------- launch ----------------

extern "C" void kernel_launch(void* const* d_in, const int* in_sizes, int n_in,
                              void* d_out, int out_size, void* d_ws, size_t ws_size,
                              hipStream_t stream) {
  const float* x = (const float*)d_in[0];   // [4,2048,4096]
  const float* W = (const float*)d_in[1];   // [11008,4096]
  float* out = (float*)d_out;               // [4,2048,11008]

  char* ws = (char*)d_ws;
  float*  amax_p = (float*)(ws + WS_AMAX_OFF);
  double* wsum_p = (double*)(ws + WS_WSUM_OFF);
  float*  scales = (float*)(ws + WS_SCALES_OFF);
  int8_t* qx = (int8_t*)(ws + WS_QX_OFF);
  int8_t* tw = (int8_t*)(ws + WS_TW_OFF);

  reduce_amax<<<1024, 256, 0, stream>>>(x, amax_p, (M_DIM * (long)K_DIM) / 4);
  reduce_wsum<<<1024, 256, 0, stream>>>(W, wsum_p, (N_DIM * (long)K_DIM) / 4);
  finalize_scales<<<1, 1024, 0, stream>>>(amax_p, wsum_p, scales);
  quant_x<<<(M_DIM * (long)K_DIM) / 16 / 256, 256, 0, stream>>>(x, scales, qx);
  tern_w<<<(N_DIM * (long)K_DIM) / 16 / 256, 256, 0, stream>>>(W, scales, tw);

  const int grid = (M_DIM / 256) * (N_DIM / 256);   // 32*43 = 1376 = 8*172
  gemm_i8<<<grid, 512, 0, stream>>>(qx, tw, scales, out);
}

// Round 4
// 535.712 us; speedup vs baseline: 1.1326x; 1.0112x over previous
//
#include <hip/hip_runtime.h>
#include <cstdint>

typedef int i32x4 __attribute__((ext_vector_type(4)));
typedef int i32x16 __attribute__((ext_vector_type(16)));

#define M_DIM 8192
#define N_DIM 11008
#define K_DIM 4096
#define NT    (K_DIM / 128)   // 32 K-tiles of BK=128

// ws layout (bytes)
#define WS_AMAX_OFF   0                      // 1024 floats
#define WS_WSUM_OFF   4096                   // 1024 doubles
#define WS_SCALES_OFF 12288                  // 4 floats
#define WS_QX_OFF     16384                  // 8192*4096 int8
#define WS_TW_OFF     (16384 + 33554432)     // 11008*4096 int8

__device__ __forceinline__ void gload_lds16(const void* g, void* l) {
  __builtin_amdgcn_global_load_lds(
      (const __attribute__((address_space(1))) unsigned int*)g,
      (__attribute__((address_space(3))) unsigned int*)l, 16, 0, 0);
}

// ---------------- reductions ----------------

__global__ void reduce_amax(const float* __restrict__ x, float* __restrict__ partial, int n4) {
  const float4* xv = (const float4*)x;
  float m = 0.f;
  for (long i = (long)blockIdx.x * blockDim.x + threadIdx.x; i < n4;
       i += (long)gridDim.x * blockDim.x) {
    float4 v = xv[i];
    m = fmaxf(m, fmaxf(fmaxf(fabsf(v.x), fabsf(v.y)), fmaxf(fabsf(v.z), fabsf(v.w))));
  }
  __shared__ float sm[256];
  sm[threadIdx.x] = m;
  __syncthreads();
  for (int s = 128; s > 0; s >>= 1) {
    if (threadIdx.x < s) sm[threadIdx.x] = fmaxf(sm[threadIdx.x], sm[threadIdx.x + s]);
    __syncthreads();
  }
  if (threadIdx.x == 0) partial[blockIdx.x] = sm[0];
}

__global__ void reduce_wsum(const float* __restrict__ w, double* __restrict__ partial, int n4) {
  const float4* wv = (const float4*)w;
  double acc = 0.0;
  for (long i = (long)blockIdx.x * blockDim.x + threadIdx.x; i < n4;
       i += (long)gridDim.x * blockDim.x) {
    float4 v = wv[i];
    acc += (double)fabsf(v.x) + (double)fabsf(v.y) + (double)fabsf(v.z) + (double)fabsf(v.w);
  }
  __shared__ double sd[256];
  sd[threadIdx.x] = acc;
  __syncthreads();
  for (int s = 128; s > 0; s >>= 1) {
    if (threadIdx.x < s) sd[threadIdx.x] += sd[threadIdx.x + s];
    __syncthreads();
  }
  if (threadIdx.x == 0) partial[blockIdx.x] = sd[0];
}

__global__ void finalize_scales(const float* __restrict__ amax_p,
                                const double* __restrict__ wsum_p,
                                float* __restrict__ scales) {
  __shared__ float sm[1024];
  __shared__ double sd[1024];
  const int t = threadIdx.x;
  sm[t] = amax_p[t];
  sd[t] = wsum_p[t];
  __syncthreads();
  for (int s = 512; s > 0; s >>= 1) {
    if (t < s) {
      sm[t] = fmaxf(sm[t], sm[t + s]);
      sd[t] += sd[t + s];
    }
    __syncthreads();
  }
  if (t == 0) {
    float act_scale = fmaxf(sm[0] / 127.0f, 1e-8f);
    float w_scale = (float)(sd[0] / (double)((long long)N_DIM * K_DIM)) + 1e-8f;
    scales[0] = act_scale;
    scales[1] = w_scale;
    scales[2] = act_scale * w_scale;
  }
}

// ---------------- quantize ----------------

__device__ __forceinline__ int quant_clip(float v, float s, float lim) {
  float r = rintf(v / s);                 // round-half-even, matches jnp.round
  r = fminf(fmaxf(r, -lim), lim);
  return (int)r;
}

__global__ void quant_x(const float* __restrict__ x, const float* __restrict__ scales,
                        int8_t* __restrict__ q) {
  const float s = scales[0];
  const long i = (long)blockIdx.x * blockDim.x + threadIdx.x;  // 16 elems/thread
  const float4* xv = (const float4*)x + (i << 2);
  i32x4 pk;
#pragma unroll
  for (int j = 0; j < 4; ++j) {
    float4 v = xv[j];
    int b0 = quant_clip(v.x, s, 127.f);
    int b1 = quant_clip(v.y, s, 127.f);
    int b2 = quant_clip(v.z, s, 127.f);
    int b3 = quant_clip(v.w, s, 127.f);
    pk[j] = (b0 & 255) | ((b1 & 255) << 8) | ((b2 & 255) << 16) | (b3 << 24);
  }
  *((i32x4*)q + i) = pk;
}

__global__ void tern_w(const float* __restrict__ w, const float* __restrict__ scales,
                       int8_t* __restrict__ q) {
  const float s = scales[1];
  const long i = (long)blockIdx.x * blockDim.x + threadIdx.x;
  const float4* wv = (const float4*)w + (i << 2);
  i32x4 pk;
#pragma unroll
  for (int j = 0; j < 4; ++j) {
    float4 v = wv[j];
    int b0 = quant_clip(v.x, s, 1.f);
    int b1 = quant_clip(v.y, s, 1.f);
    int b2 = quant_clip(v.z, s, 1.f);
    int b3 = quant_clip(v.w, s, 1.f);
    pk[j] = (b0 & 255) | ((b1 & 255) << 8) | ((b2 & 255) << 16) | (b3 << 24);
  }
  *((i32x4*)q + i) = pk;
}

// ---------------- int8 GEMM: 256x256 tile, BK=128, barrier-minimal pipeline ----------------
// 8 waves (2m x 4n), per-wave 128x64 output = acc[4][2] of 32x32 i32 tiles.
// Intra-tile: NO barriers (staging targets the other double-buffer -> no hazard).
// One-slice-ahead register prefetch: slice ks+1's 6 ds_read_b128 issue before
// slice ks's 8-MFMA cluster; compiler inserts counted lgkmcnt for the deps.
// Tile boundary only: lgkm0; bar; stage(t+2,p0 -> cur); vmcnt(2) [counted, queue
// = 2x(t+1p0) + 6x(t+1p123) + 2x(t+2p0) -> drains all 8 of t+1]; bar; fence.
// Swizzle (rule #21): LDS slot (row,c) holds global chunk c^(row&7).

__global__ __launch_bounds__(512, 2) void gemm_i8(const int8_t* __restrict__ qx,
                                                  const int8_t* __restrict__ tw,
                                                  const float* __restrict__ scales,
                                                  float* __restrict__ out) {
  __shared__ __align__(16) int8_t lds[4][32768];   // A0,A1,B0,B1

  const int tid = threadIdx.x;
  const int l = tid & 63;
  const int w = tid >> 6;

  // ---- block -> tile mapping, 2D XCD chunk (bijective: 1376 = 8*172) ----
  const int bid = blockIdx.x;
  const int xcd = bid & 7;
  const int local = bid >> 3;               // 0..171
  const int ni = local >> 2;                // 0..42
  const int mi = (xcd << 2) + (local & 3);  // 0..31
  const long row0 = (long)mi << 8;
  const long col0 = (long)ni << 8;

  // ---- staging source (pre-swizzled global chunk) ----
  const int srow = tid >> 3;                // 0..63
  const int sch = (tid & 7) ^ (srow & 7);
  const int8_t* pA = qx + (row0 + srow) * (long)K_DIM + (sch << 4);
  const int8_t* pB = tw + (col0 + srow) * (long)K_DIM + (sch << 4);
  const int ldst = w << 10;                 // wave-uniform LDS slice

  // stage one part (rows part*64 .. part*64+63) of a K-tile: 2 gload_lds per wave
  auto stage_part = [&](int8_t* dA, int8_t* dB, int kt, int part) {
    const long cb = (long)kt << 7;
    gload_lds16(pA + cb + ((long)part * 64) * K_DIM, dA + part * 8192 + ldst);
    gload_lds16(pB + cb + ((long)part * 64) * K_DIM, dB + part * 8192 + ldst);
  };

  // ---- read-side offsets ----
  const int lane31 = l & 31;
  const int khalf = l >> 5;
  const int swz = l & 7;                    // = row&7 (fragment row bases 32-aligned)
  int cOff[4];
#pragma unroll
  for (int ks = 0; ks < 4; ++ks) cOff[ks] = ((((ks << 1) | khalf) ^ swz) << 4);
  const int aRow = ((w >> 2) * 128 + lane31) * 128;   // + mf*4096
  const int bRow0 = ((w & 3) * 64 + lane31) * 128;
  const int bRow1 = bRow0 + 32 * 128;

  i32x16 acc[4][2];
#pragma unroll
  for (int mf = 0; mf < 4; ++mf)
#pragma unroll
    for (int nf = 0; nf < 2; ++nf)
#pragma unroll
      for (int e = 0; e < 16; ++e) acc[mf][nf][e] = 0;

  // ---- prologue: tile0 fully staged, tile1 part0 in flight ----
#pragma unroll
  for (int p = 0; p < 4; ++p) stage_part(lds[0], lds[2], 0, p);
  stage_part(lds[1], lds[3], 1, 0);
  asm volatile("s_waitcnt vmcnt(2)" ::: "memory");
  __builtin_amdgcn_s_barrier();
  asm volatile("" ::: "memory");

  for (int t = 0; t < NT; ++t) {
    int8_t* cA = lds[t & 1];
    int8_t* cB = lds[2 + (t & 1)];
    int8_t* nA = lds[(t & 1) ^ 1];
    int8_t* nB = lds[2 + ((t & 1) ^ 1)];
    const bool pf = (t + 1 < NT);

    // register-pipelined slices: double-buffered fragment sets
    i32x4 af[2][4], bf[2][2];
#pragma unroll
    for (int mf = 0; mf < 4; ++mf)
      af[0][mf] = *(const i32x4*)(cA + aRow + mf * 4096 + cOff[0]);
    bf[0][0] = *(const i32x4*)(cB + bRow0 + cOff[0]);
    bf[0][1] = *(const i32x4*)(cB + bRow1 + cOff[0]);

#pragma unroll
    for (int ks = 0; ks < 4; ++ks) {
      const int c = ks & 1;
      const int n = c ^ 1;
      if (ks < 3) {
#pragma unroll
        for (int mf = 0; mf < 4; ++mf)
          af[n][mf] = *(const i32x4*)(cA + aRow + mf * 4096 + cOff[ks + 1]);
        bf[n][0] = *(const i32x4*)(cB + bRow0 + cOff[ks + 1]);
        bf[n][1] = *(const i32x4*)(cB + bRow1 + cOff[ks + 1]);
        if (pf) stage_part(nA, nB, t + 1, ks + 1);   // spread 6 gloads over tile body
      }
      __builtin_amdgcn_s_setprio(1);
#pragma unroll
      for (int mf = 0; mf < 4; ++mf) {
        acc[mf][0] = __builtin_amdgcn_mfma_i32_32x32x32_i8(af[c][mf], bf[c][0], acc[mf][0], 0, 0, 0);
        acc[mf][1] = __builtin_amdgcn_mfma_i32_32x32x32_i8(af[c][mf], bf[c][1], acc[mf][1], 0, 0, 0);
      }
      __builtin_amdgcn_s_setprio(0);
    }

    // ---- tile boundary (only sync point) ----
    if (pf) {
      asm volatile("s_waitcnt lgkmcnt(0)" ::: "memory");  // own reads of cur done
      __builtin_amdgcn_s_barrier();                       // all waves' reads of cur done
      asm volatile("" ::: "memory");
      if (t + 2 < NT) {
        stage_part(cA, cB, t + 2, 0);                     // overwrite freed cur
        asm volatile("s_waitcnt vmcnt(2)" ::: "memory");  // t+1's 8 loads complete
      } else {
        asm volatile("s_waitcnt vmcnt(0)" ::: "memory");
      }
      __builtin_amdgcn_s_barrier();                       // nxt visible to all
      asm volatile("" ::: "memory");
    }
  }

  // ---- epilogue: C/D 32x32 layout: col=lane&31, row=(reg&3)+8*(reg>>2)+4*(lane>>5) ----
  const float osc = scales[2];
  const int rbase = khalf << 2;
#pragma unroll
  for (int mf = 0; mf < 4; ++mf)
#pragma unroll
    for (int nf = 0; nf < 2; ++nf)
#pragma unroll
      for (int reg = 0; reg < 16; ++reg) {
        int rr = (w >> 2) * 128 + mf * 32 + rbase + (reg & 3) + ((reg >> 2) << 3);
        int cc = (w & 3) * 64 + nf * 32 + lane31;
        out[(row0 + rr) * (long)N_DIM + (col0 + cc)] = (float)acc[mf][nf][reg] * osc;
      }
}

// ---------------- launch ----------------

extern "C" void kernel_launch(void* const* d_in, const int* in_sizes, int n_in,
                              void* d_out, int out_size, void* d_ws, size_t ws_size,
                              hipStream_t stream) {
  const float* x = (const float*)d_in[0];   // [4,2048,4096]
  const float* W = (const float*)d_in[1];   // [11008,4096]
  float* out = (float*)d_out;               // [4,2048,11008]

  char* ws = (char*)d_ws;
  float*  amax_p = (float*)(ws + WS_AMAX_OFF);
  double* wsum_p = (double*)(ws + WS_WSUM_OFF);
  float*  scales = (float*)(ws + WS_SCALES_OFF);
  int8_t* qx = (int8_t*)(ws + WS_QX_OFF);
  int8_t* tw = (int8_t*)(ws + WS_TW_OFF);

  reduce_amax<<<1024, 256, 0, stream>>>(x, amax_p, (M_DIM * (long)K_DIM) / 4);
  reduce_wsum<<<1024, 256, 0, stream>>>(W, wsum_p, (N_DIM * (long)K_DIM) / 4);
  finalize_scales<<<1, 1024, 0, stream>>>(amax_p, wsum_p, scales);
  quant_x<<<(M_DIM * (long)K_DIM) / 16 / 256, 256, 0, stream>>>(x, scales, qx);
  tern_w<<<(N_DIM * (long)K_DIM) / 16 / 256, 256, 0, stream>>>(W, scales, tw);

  const int grid = (M_DIM / 256) * (N_DIM / 256);   // 32*43 = 1376 = 8*172
  gemm_i8<<<grid, 512, 0, stream>>>(qx, tw, scales, out);
}